// Round 8
// baseline (379.482 us; speedup 1.0000x reference)
//
#include <hip/hip_runtime.h>
#include <hip/hip_bf16.h>

typedef __bf16 bf16;
typedef __bf16 bf16x4 __attribute__((ext_vector_type(4)));
typedef __bf16 bf16x8 __attribute__((ext_vector_type(8)));
typedef float f32x4 __attribute__((ext_vector_type(4)));
typedef float f32x16 __attribute__((ext_vector_type(16)));

#define NB 4
#define SEQ 2048
#define DM 1024
#define NH 16
#define HDIM 64
#define MTOT (NB*SEQ)   // 8192
#define BH_STRIDE (SEQ * HDIM)   // 131072 elems per (b,h) for Q/K/V

// 0.125 * log2(e): folded into Q at the QKV epilogue so softmax uses exp2
#define QSCALE 0.18033688011112042f

// async global -> LDS, 16 bytes per lane
#define ASYNC16(ldsp, gp) __builtin_amdgcn_global_load_lds( \
    (const __attribute__((address_space(1))) void*)(gp),    \
    (__attribute__((address_space(3))) void*)(ldsp), 16, 0, 0)

// ---------------- conversion kernels ----------------
__global__ void cvt_x_kernel(const float* __restrict__ x, bf16* __restrict__ xb, int n4) {
  int i = blockIdx.x * blockDim.x + threadIdx.x;
  int stride = gridDim.x * blockDim.x;
  for (; i < n4; i += stride) {
    float4 v = ((const float4*)x)[i];
    bf16x4 o = {(bf16)v.x, (bf16)v.y, (bf16)v.z, (bf16)v.w};
    ((bf16x4*)xb)[i] = o;
  }
}

// transpose + convert: wt[z][n][k] = w_z[k][n], bf16
__global__ void cvt_w_kernel(const float* __restrict__ w0, const float* __restrict__ w1,
                             const float* __restrict__ w2, const float* __restrict__ w3,
                             bf16* __restrict__ wt) {
  __shared__ float t[32][33];
  const float* w = blockIdx.z == 0 ? w0 : blockIdx.z == 1 ? w1 : blockIdx.z == 2 ? w2 : w3;
  bf16* o = wt + (size_t)blockIdx.z * DM * DM;
  int n0 = blockIdx.x * 32, k0 = blockIdx.y * 32;
  int tx = threadIdx.x, ty = threadIdx.y;   // 32 x 8
  #pragma unroll
  for (int i = 0; i < 4; i++) t[ty + 8*i][tx] = w[(size_t)(k0 + ty + 8*i) * DM + n0 + tx];
  __syncthreads();
  #pragma unroll
  for (int i = 0; i < 4; i++) o[(size_t)(n0 + ty + 8*i) * DM + k0 + tx] = (bf16)t[tx][ty + 8*i];
}

// ---------------- 128x128 bf16 GEMM, A[M][K] * Bt[N][K]^T ----------------
// EPI 0: QKV epilogue -> fragment-ordered layouts for 32x32x16 MFMA attention.
//   Q/K per (b,h): off = (s>>5)*2048 + (hd>>4)*512 + ((hd>>3)&1)*256 + (s&31)*8 + (hd&7)
//   V   per (b,h): off = (s>>6)*4096 + (hd>>5)*2048 + ((s>>4)&3)*512 + ((s>>3)&1)*256
//                        + (hd&31)*8 + (s&7)
// EPI 1: output projection epilogue (fp32 write + bias)
template<int EPI>
__global__ __launch_bounds__(256) void gemm128(
    const bf16* __restrict__ A, const bf16* __restrict__ Bt,
    const float* __restrict__ bq, const float* __restrict__ bk, const float* __restrict__ bv,
    bf16* __restrict__ oq, bf16* __restrict__ ok, bf16* __restrict__ ovt,
    float* __restrict__ of) {
  const int tid = threadIdx.x;
  const int lane = tid & 63;
  const int wid = tid >> 6;
  const int wr = wid >> 1, wc = wid & 1;     // 2x2 waves, each 64x64
  const int bm = blockIdx.y * 128;
  const int bn = blockIdx.x * 128;

  __shared__ __align__(16) bf16 As[2][128 * 32];
  __shared__ __align__(16) bf16 Bs[2][128 * 32];

  f32x4 acc[4][4] = {};

  const bf16* ga = A  + (size_t)(bm + (tid >> 2)) * DM + (tid & 3) * 8;
  const bf16* gb = Bt + (size_t)(bn + (tid >> 2)) * DM + (tid & 3) * 8;

  // stage K-tile 0 into buffer 0
  ASYNC16(&As[0][tid * 8], ga);
  ASYNC16(&As[0][2048 + tid * 8], ga + 64 * DM);
  ASYNC16(&Bs[0][tid * 8], gb);
  ASYNC16(&Bs[0][2048 + tid * 8], gb + 64 * DM);

  const int r0 = lane & 15;
  const int kc = (lane >> 4) * 8;

  for (int kt = 0; kt < DM / 32; ++kt) {
    const int cur = kt & 1;
    __syncthreads();
    if (kt + 1 < DM / 32) {
      const int nk = (kt + 1) * 32;
      ASYNC16(&As[cur ^ 1][tid * 8], ga + nk);
      ASYNC16(&As[cur ^ 1][2048 + tid * 8], ga + 64 * DM + nk);
      ASYNC16(&Bs[cur ^ 1][tid * 8], gb + nk);
      ASYNC16(&Bs[cur ^ 1][2048 + tid * 8], gb + 64 * DM + nk);
    }
    bf16x8 af[4], bfr[4];
    #pragma unroll
    for (int i = 0; i < 4; i++) {
      af[i]  = *(const bf16x8*)&As[cur][(wr * 64 + i * 16 + r0) * 32 + kc];
      bfr[i] = *(const bf16x8*)&Bs[cur][(wc * 64 + i * 16 + r0) * 32 + kc];
    }
    #pragma unroll
    for (int i = 0; i < 4; i++)
      #pragma unroll
      for (int j = 0; j < 4; j++)
        acc[i][j] = __builtin_amdgcn_mfma_f32_16x16x32_bf16(af[i], bfr[j], acc[i][j], 0, 0, 0);
  }

  if (EPI == 0) {
    const int which = bn >> 10;                       // block-uniform (0:q 1:k 2:v)
    const float* bp = which == 0 ? bq : which == 1 ? bk : bv;
    const float scale = (which == 0) ? QSCALE : 1.0f;
    #pragma unroll
    for (int j = 0; j < 4; j++) {
      const int n = bn + wc * 64 + j * 16 + r0;
      const int dcol = n & 1023;
      const int h = dcol >> 6, hd = dcol & 63;
      const float bias = bp[dcol];
      // hd-dependent offsets, hoisted
      const int qk_d = (hd >> 4) * 512 + ((hd >> 3) & 1) * 256 + (hd & 7);
      const int v_d  = (hd >> 5) * 2048 + (hd & 31) * 8;
      #pragma unroll
      for (int i = 0; i < 4; i++)
        #pragma unroll
        for (int r = 0; r < 4; r++) {
          const int m = bm + wr * 64 + i * 16 + (lane >> 4) * 4 + r;
          const int b_ = m >> 11, s_ = m & 2047;
          const float v = (acc[i][j][r] + bias) * scale;
          if (which <= 1) {
            const size_t off = (size_t)(b_ * NH + h) * BH_STRIDE
                             + (s_ >> 5) * 2048 + (s_ & 31) * 8 + qk_d;
            (which == 0 ? oq : ok)[off] = (bf16)v;
          } else {
            const size_t off = (size_t)(b_ * NH + h) * BH_STRIDE
                             + (s_ >> 6) * 4096 + ((s_ >> 4) & 3) * 512
                             + ((s_ >> 3) & 1) * 256 + (s_ & 7) + v_d;
            ovt[off] = (bf16)v;
          }
        }
    }
  } else {
    #pragma unroll
    for (int j = 0; j < 4; j++) {
      const int n = bn + wc * 64 + j * 16 + r0;
      const float bias = bq[n];                        // o_b
      #pragma unroll
      for (int i = 0; i < 4; i++)
        #pragma unroll
        for (int r = 0; r < 4; r++) {
          const int m = bm + wr * 64 + i * 16 + (lane >> 4) * 4 + r;
          of[(size_t)m * DM + n] = acc[i][j][r] + bias;
        }
    }
  }
}

// ---------------- flash attention (32x32x16 MFMA, swapped operands) ----------------
// grid (S/128, H, B), 256 threads = 4 waves, each wave owns 32 q-rows.
// QK^T: sc = mfma32(K_frag, Q_frag) -> lane holds S[kv][q=lane&31], 32 scores
//   at kv = kvt*32 + (reg&3) + 8*(reg>>2) + 4*(lane>>5). Row softmax: 31 in-lane
//   fmax + 1 shfl_xor(32); m/l per-lane scalars. P staged in pad-68 row-major LDS
//   (b64 writes, b128 reads, 2-way = free). PV: oacc = mfma32(Vt_frag, P_frag) ->
//   lane holds O[q][d = dt*32 + 8*rg + 4*hi + e], stored as 8B vectors.
__global__ __launch_bounds__(256) void attn_kernel(
    const bf16* __restrict__ Q, const bf16* __restrict__ Kf, const bf16* __restrict__ Vf,
    bf16* __restrict__ O) {
  const int tid = threadIdx.x;
  const int lane = tid & 63;
  const int wid = tid >> 6;
  const int hi = lane >> 5;
  const int q5 = lane & 31;
  const int qt = blockIdx.x;
  const int h = blockIdx.y;
  const int b = blockIdx.z;

  const bf16* qp = Q  + (size_t)(b * NH + h) * BH_STRIDE + qt * 8192;
  const bf16* kp = Kf + (size_t)(b * NH + h) * BH_STRIDE;
  const bf16* vp = Vf + (size_t)(b * NH + h) * BH_STRIDE;

  __shared__ __align__(16) bf16 KsF[8192];       // 2 x 4096 double buffer
  __shared__ __align__(16) bf16 VsF[8192];       // 2 x 4096 double buffer
  __shared__ __align__(16) bf16 Pp[4][32 * 68];  // per-wave P[q][kv], row stride 68

  // ---- stage Q (128 q-rows, 8192 elems) into KsF, grab fragments ----
  ASYNC16(&KsF[tid * 8], qp + tid * 8);
  ASYNC16(&KsF[2048 + tid * 8], qp + 2048 + tid * 8);
  ASYNC16(&KsF[4096 + tid * 8], qp + 4096 + tid * 8);
  ASYNC16(&KsF[6144 + tid * 8], qp + 6144 + tid * 8);
  __syncthreads();
  bf16x8 qf[4];
  #pragma unroll
  for (int ks = 0; ks < 4; ks++)
    qf[ks] = *(const bf16x8*)&KsF[wid * 2048 + ks * 512 + hi * 256 + q5 * 8];
  __syncthreads();   // all waves done reading Q

  // ---- stage K0 / V0 ----
  ASYNC16(&KsF[tid * 8], kp + tid * 8);
  ASYNC16(&KsF[2048 + tid * 8], kp + 2048 + tid * 8);
  ASYNC16(&VsF[tid * 8], vp + tid * 8);
  ASYNC16(&VsF[2048 + tid * 8], vp + 2048 + tid * 8);
  __syncthreads();

  float m_run = -1e30f, l_run = 0.f;
  f32x16 oaccA = {}, oaccB = {};

  bf16* pwb = &Pp[wid][q5 * 68 + hi * 4];        // + kvt*32 + rg*8
  const bf16* prd = &Pp[wid][q5 * 68 + hi * 8];  // + kvs*16

  for (int kt = 0; kt < SEQ / 64; ++kt) {
    const int curo = (kt & 1) * 4096;
    if (kt + 1 < SEQ / 64) {
      const int nxo = curo ^ 4096;
      const bf16* gk = kp + (size_t)(kt + 1) * 4096;
      ASYNC16(&KsF[nxo + tid * 8], gk + tid * 8);
      ASYNC16(&KsF[nxo + 2048 + tid * 8], gk + 2048 + tid * 8);
      const bf16* gv = vp + (size_t)(kt + 1) * 4096;
      ASYNC16(&VsF[nxo + tid * 8], gv + tid * 8);
      ASYNC16(&VsF[nxo + 2048 + tid * 8], gv + 2048 + tid * 8);
    }

    // ---- swapped QK^T: 2 x (32kv x 32q), K = 4 ksteps of 16 ----
    f32x16 sc0 = {}, sc1 = {};
    __builtin_amdgcn_s_setprio(1);
    #pragma unroll
    for (int ks = 0; ks < 4; ks++) {
      const bf16x8 kf0 = *(const bf16x8*)&KsF[curo + ks * 512 + hi * 256 + q5 * 8];
      sc0 = __builtin_amdgcn_mfma_f32_32x32x16_bf16(kf0, qf[ks], sc0, 0, 0, 0);
      const bf16x8 kf1 = *(const bf16x8*)&KsF[curo + 2048 + ks * 512 + hi * 256 + q5 * 8];
      sc1 = __builtin_amdgcn_mfma_f32_32x32x16_bf16(kf1, qf[ks], sc1, 0, 0, 0);
    }
    __builtin_amdgcn_s_setprio(0);

    // ---- online softmax: 31 in-lane fmax + 1 shfl; defer-max (THR=8, log2) ----
    float pmax = sc0[0];
    #pragma unroll
    for (int r = 1; r < 16; r++) pmax = fmaxf(pmax, sc0[r]);
    #pragma unroll
    for (int r = 0; r < 16; r++) pmax = fmaxf(pmax, sc1[r]);
    pmax = fmaxf(pmax, __shfl_xor(pmax, 32));

    if (__any(pmax > m_run + 8.f)) {
      const float mnew = fmaxf(m_run, pmax);
      const float fac = exp2f(m_run - mnew);
      l_run *= fac;
      #pragma unroll
      for (int r = 0; r < 16; r++) { oaccA[r] *= fac; oaccB[r] *= fac; }
      m_run = mnew;
    }

    float psum = 0.f;
    #pragma unroll
    for (int rg = 0; rg < 4; rg++) {
      bf16x4 pk0, pk1;
      #pragma unroll
      for (int e = 0; e < 4; e++) {
        const float pv0 = exp2f(sc0[rg * 4 + e] - m_run);
        psum += pv0;
        pk0[e] = (bf16)pv0;
        const float pv1 = exp2f(sc1[rg * 4 + e] - m_run);
        psum += pv1;
        pk1[e] = (bf16)pv1;
      }
      *(bf16x4*)(pwb + rg * 8) = pk0;        // P[q][rg*8 + 4hi .. +3]
      *(bf16x4*)(pwb + 32 + rg * 8) = pk1;   // P[q][32 + rg*8 + 4hi .. +3]
    }
    psum += __shfl_xor(psum, 32);
    l_run += psum;

    // ---- swapped PV: O^T[d][q], d-tiles x 4 ksteps of 16 kv ----
    __builtin_amdgcn_s_setprio(1);
    #pragma unroll
    for (int kvs = 0; kvs < 4; kvs++) {
      const bf16x8 pf = *(const bf16x8*)(prd + kvs * 16);
      const bf16x8 vf0 = *(const bf16x8*)&VsF[curo + kvs * 512 + hi * 256 + q5 * 8];
      oaccA = __builtin_amdgcn_mfma_f32_32x32x16_bf16(vf0, pf, oaccA, 0, 0, 0);
      const bf16x8 vf1 = *(const bf16x8*)&VsF[curo + 2048 + kvs * 512 + hi * 256 + q5 * 8];
      oaccB = __builtin_amdgcn_mfma_f32_32x32x16_bf16(vf1, pf, oaccB, 0, 0, 0);
    }
    __builtin_amdgcn_s_setprio(0);
    __syncthreads();   // compute on cur done + next tile's staging landed
  }

  // ---- epilogue: normalize, write attn output [B][S][D] (bf16, 8B vectors) ----
  const float inv = 1.0f / l_run;
  const int qrow = qt * 128 + wid * 32 + q5;
  bf16* ob = (bf16*)&O[((size_t)b * SEQ + qrow) * DM + h * HDIM + hi * 4];
  #pragma unroll
  for (int rg = 0; rg < 4; rg++) {
    bf16x4 ovA, ovB;
    #pragma unroll
    for (int e = 0; e < 4; e++) {
      ovA[e] = (bf16)(oaccA[rg * 4 + e] * inv);
      ovB[e] = (bf16)(oaccB[rg * 4 + e] * inv);
    }
    *(bf16x4*)(ob + rg * 8) = ovA;
    *(bf16x4*)(ob + 32 + rg * 8) = ovB;
  }
}

// ---------------- launcher ----------------
extern "C" void kernel_launch(void* const* d_in, const int* in_sizes, int n_in,
                              void* d_out, int out_size, void* d_ws, size_t ws_size,
                              hipStream_t stream) {
  (void)in_sizes; (void)n_in; (void)out_size; (void)ws_size;
  const float* x   = (const float*)d_in[0];
  const float* q_w = (const float*)d_in[1];
  const float* q_b = (const float*)d_in[2];
  const float* k_w = (const float*)d_in[3];
  const float* k_b = (const float*)d_in[4];
  const float* v_w = (const float*)d_in[5];
  const float* v_b = (const float*)d_in[6];
  const float* o_w = (const float*)d_in[7];
  const float* o_b = (const float*)d_in[8];
  float* out = (float*)d_out;

  char* p = (char*)d_ws;
  bf16* xb = (bf16*)p;  p += (size_t)MTOT * DM * 2;   // x bf16; reused later as attn output
  bf16* wt = (bf16*)p;  p += (size_t)4 * DM * DM * 2; // transposed bf16 weights [4][N][K]
  bf16* qq = (bf16*)p;  p += (size_t)MTOT * DM * 2;   // Q fragment-ordered (pre-scaled)
  bf16* kk = (bf16*)p;  p += (size_t)MTOT * DM * 2;   // K fragment-ordered
  bf16* vt = (bf16*)p;  p += (size_t)MTOT * DM * 2;   // V fragment-ordered

  cvt_x_kernel<<<1024, 256, 0, stream>>>(x, xb, MTOT * DM / 4);
  cvt_w_kernel<<<dim3(32, 32, 4), dim3(32, 8), 0, stream>>>(q_w, k_w, v_w, o_w, wt);

  // QKV projection: M=8192, N=3072 (q|k|v), K=1024
  gemm128<0><<<dim3(24, 64), 256, 0, stream>>>(xb, wt, q_b, k_b, v_b, qq, kk, vt, nullptr);

  // flash attention, writes [B][S][D] bf16 into xb (x no longer needed)
  attn_kernel<<<dim3(SEQ / 128, NH, NB), 256, 0, stream>>>(qq, kk, vt, xb);

  // output projection: M=8192, N=1024, K=1024, fp32 out + bias
  gemm128<1><<<dim3(8, 64), 256, 0, stream>>>(xb, wt + (size_t)3 * DM * DM, o_b, nullptr, nullptr,
                                              nullptr, nullptr, nullptr, out);
}

// Round 9
// 344.031 us; speedup vs baseline: 1.1030x; 1.1030x over previous
//
#include <hip/hip_runtime.h>
#include <hip/hip_bf16.h>

typedef __bf16 bf16;
typedef __bf16 bf16x2 __attribute__((ext_vector_type(2)));
typedef __bf16 bf16x4 __attribute__((ext_vector_type(4)));
typedef __bf16 bf16x8 __attribute__((ext_vector_type(8)));
typedef float f32x4 __attribute__((ext_vector_type(4)));
typedef float f32x16 __attribute__((ext_vector_type(16)));

#define NB 4
#define SEQ 2048
#define DM 1024
#define NH 16
#define HDIM 64
#define MTOT (NB*SEQ)   // 8192
#define BH_STRIDE (SEQ * HDIM)   // 131072 elems per (b,h) for Q/K/V

// 0.125 * log2(e): folded into Q at the QKV epilogue so softmax uses exp2
#define QSCALE 0.18033688011112042f

// async global -> LDS, 16 bytes per lane
#define ASYNC16(ldsp, gp) __builtin_amdgcn_global_load_lds( \
    (const __attribute__((address_space(1))) void*)(gp),    \
    (__attribute__((address_space(3))) void*)(ldsp), 16, 0, 0)

// ---------------- conversion kernels ----------------
__global__ void cvt_x_kernel(const float* __restrict__ x, bf16* __restrict__ xb, int n4) {
  int i = blockIdx.x * blockDim.x + threadIdx.x;
  int stride = gridDim.x * blockDim.x;
  for (; i < n4; i += stride) {
    float4 v = ((const float4*)x)[i];
    bf16x4 o = {(bf16)v.x, (bf16)v.y, (bf16)v.z, (bf16)v.w};
    ((bf16x4*)xb)[i] = o;
  }
}

// transpose + convert: wt[z][n][k] = w_z[k][n], bf16
__global__ void cvt_w_kernel(const float* __restrict__ w0, const float* __restrict__ w1,
                             const float* __restrict__ w2, const float* __restrict__ w3,
                             bf16* __restrict__ wt) {
  __shared__ float t[32][33];
  const float* w = blockIdx.z == 0 ? w0 : blockIdx.z == 1 ? w1 : blockIdx.z == 2 ? w2 : w3;
  bf16* o = wt + (size_t)blockIdx.z * DM * DM;
  int n0 = blockIdx.x * 32, k0 = blockIdx.y * 32;
  int tx = threadIdx.x, ty = threadIdx.y;   // 32 x 8
  #pragma unroll
  for (int i = 0; i < 4; i++) t[ty + 8*i][tx] = w[(size_t)(k0 + ty + 8*i) * DM + n0 + tx];
  __syncthreads();
  #pragma unroll
  for (int i = 0; i < 4; i++) o[(size_t)(n0 + ty + 8*i) * DM + k0 + tx] = (bf16)t[tx][ty + 8*i];
}

// ---------------- 128x128 bf16 GEMM, A[M][K] * Bt[N][K]^T ----------------
// 1D grid with XCD-aware swizzle (T1). NX = tiles along N.
// EPI 0: QKV epilogue -> fragment-ordered layouts for 32x32x16 MFMA attention.
//   Q/K per (b,h): off = (s>>5)*2048 + (hd>>4)*512 + ((hd>>3)&1)*256 + (s&31)*8 + (hd&7)
//   V   per (b,h): off = (s>>6)*4096 + (hd>>5)*2048 + ((s>>4)&3)*512 + ((s>>3)&1)*256
//                        + (hd&31)*8 + (s&7)
// EPI 1: output projection epilogue (fp32 write + bias)
template<int EPI, int NX>
__global__ __launch_bounds__(256) void gemm128(
    const bf16* __restrict__ A, const bf16* __restrict__ Bt,
    const float* __restrict__ bq, const float* __restrict__ bk, const float* __restrict__ bv,
    bf16* __restrict__ oq, bf16* __restrict__ ok, bf16* __restrict__ ovt,
    float* __restrict__ of) {
  const int tid = threadIdx.x;
  const int lane = tid & 63;
  const int wid = tid >> 6;
  const int wr = wid >> 1, wc = wid & 1;     // 2x2 waves, each 64x64
  // XCD-aware swizzle: contiguous chunk of tiles per XCD (nwg % 8 == 0)
  const int nwg = NX * 64;
  const int wg = (blockIdx.x & 7) * (nwg >> 3) + (blockIdx.x >> 3);
  const int bm = (wg / NX) * 128;
  const int bn = (wg % NX) * 128;

  __shared__ __align__(16) bf16 As[2][128 * 32];
  __shared__ __align__(16) bf16 Bs[2][128 * 32];

  f32x4 acc[4][4] = {};

  const bf16* ga = A  + (size_t)(bm + (tid >> 2)) * DM + (tid & 3) * 8;
  const bf16* gb = Bt + (size_t)(bn + (tid >> 2)) * DM + (tid & 3) * 8;

  // stage K-tile 0 into buffer 0
  ASYNC16(&As[0][tid * 8], ga);
  ASYNC16(&As[0][2048 + tid * 8], ga + 64 * DM);
  ASYNC16(&Bs[0][tid * 8], gb);
  ASYNC16(&Bs[0][2048 + tid * 8], gb + 64 * DM);

  const int r0 = lane & 15;
  const int kc = (lane >> 4) * 8;

  for (int kt = 0; kt < DM / 32; ++kt) {
    const int cur = kt & 1;
    __syncthreads();
    if (kt + 1 < DM / 32) {
      const int nk = (kt + 1) * 32;
      ASYNC16(&As[cur ^ 1][tid * 8], ga + nk);
      ASYNC16(&As[cur ^ 1][2048 + tid * 8], ga + 64 * DM + nk);
      ASYNC16(&Bs[cur ^ 1][tid * 8], gb + nk);
      ASYNC16(&Bs[cur ^ 1][2048 + tid * 8], gb + 64 * DM + nk);
    }
    bf16x8 af[4], bfr[4];
    #pragma unroll
    for (int i = 0; i < 4; i++) {
      af[i]  = *(const bf16x8*)&As[cur][(wr * 64 + i * 16 + r0) * 32 + kc];
      bfr[i] = *(const bf16x8*)&Bs[cur][(wc * 64 + i * 16 + r0) * 32 + kc];
    }
    #pragma unroll
    for (int i = 0; i < 4; i++)
      #pragma unroll
      for (int j = 0; j < 4; j++)
        acc[i][j] = __builtin_amdgcn_mfma_f32_16x16x32_bf16(af[i], bfr[j], acc[i][j], 0, 0, 0);
  }

  if (EPI == 0) {
    const int which = bn >> 10;                       // block-uniform (0:q 1:k 2:v)
    const float* bp = which == 0 ? bq : which == 1 ? bk : bv;
    const float scale = (which == 0) ? QSCALE : 1.0f;
    #pragma unroll
    for (int j = 0; j < 4; j++) {
      const int n = bn + wc * 64 + j * 16 + r0;
      const int dcol = n & 1023;
      const int h = dcol >> 6, hd = dcol & 63;
      const float bias = bp[dcol];
      // hd-dependent offsets, hoisted
      const int qk_d = (hd >> 4) * 512 + ((hd >> 3) & 1) * 256 + (hd & 7);
      const int v_d  = (hd >> 5) * 2048 + (hd & 31) * 8;
      #pragma unroll
      for (int i = 0; i < 4; i++)
        #pragma unroll
        for (int r = 0; r < 4; r++) {
          const int m = bm + wr * 64 + i * 16 + (lane >> 4) * 4 + r;
          const int b_ = m >> 11, s_ = m & 2047;
          const float v = (acc[i][j][r] + bias) * scale;
          if (which <= 1) {
            const size_t off = (size_t)(b_ * NH + h) * BH_STRIDE
                             + (s_ >> 5) * 2048 + (s_ & 31) * 8 + qk_d;
            (which == 0 ? oq : ok)[off] = (bf16)v;
          } else {
            const size_t off = (size_t)(b_ * NH + h) * BH_STRIDE
                             + (s_ >> 6) * 4096 + ((s_ >> 4) & 3) * 512
                             + ((s_ >> 3) & 1) * 256 + (s_ & 7) + v_d;
            ovt[off] = (bf16)v;
          }
        }
    }
  } else {
    #pragma unroll
    for (int j = 0; j < 4; j++) {
      const int n = bn + wc * 64 + j * 16 + r0;
      const float bias = bq[n];                        // o_b
      #pragma unroll
      for (int i = 0; i < 4; i++)
        #pragma unroll
        for (int r = 0; r < 4; r++) {
          const int m = bm + wr * 64 + i * 16 + (lane >> 4) * 4 + r;
          of[(size_t)m * DM + n] = acc[i][j][r] + bias;
        }
    }
  }
}

// ---------------- flash attention (32x32x16 MFMA, swapped operands, P in regs) ----------------
// 1D grid 1024 blocks, XCD-swizzled so all qt-blocks of 8 (b,h) pairs share an XCD L2.
// 256 threads = 4 waves, each wave owns 32 q-rows, KV tile 64.
// QK^T: sc = mfma32(K_frag, Q_frag) -> lane holds S[kv][q=lane&31], kv = (r&3)+8*(r>>2)+4*hi.
// Softmax lane-local (31 fmax + 1 shfl). P packed to bf16x2 u32s in-register;
// PV B-fragments assembled via one lane<->lane^32 exchange (shfl_xor 32) per u32 pair:
//   frag(kvs): w0/w1 from hi0-lane's Pa/Pb[t][2k1+hi], w2/w3 from hi1-lane's same.
// PV: oacc = mfma32(Vt_frag, pf). No P LDS buffer -> 32 KB LDS -> 4 blocks/CU.
__global__ __launch_bounds__(256) void attn_kernel(
    const bf16* __restrict__ Q, const bf16* __restrict__ Kf, const bf16* __restrict__ Vf,
    bf16* __restrict__ O) {
  const int tid = threadIdx.x;
  const int lane = tid & 63;
  const int wid = tid >> 6;
  const int hi = lane >> 5;
  const int q5 = lane & 31;
  // XCD swizzle: wg = xcd*128 + idx ; qt fastest, then h, then b
  const int wg = (blockIdx.x & 7) * 128 + (blockIdx.x >> 3);
  const int qt = wg & 15;
  const int h = (wg >> 4) & 15;
  const int b = wg >> 8;

  const bf16* qp = Q  + (size_t)(b * NH + h) * BH_STRIDE + qt * 8192;
  const bf16* kp = Kf + (size_t)(b * NH + h) * BH_STRIDE;
  const bf16* vp = Vf + (size_t)(b * NH + h) * BH_STRIDE;

  __shared__ __align__(16) bf16 KsF[8192];       // 2 x 4096 double buffer
  __shared__ __align__(16) bf16 VsF[8192];       // 2 x 4096 double buffer

  // ---- stage Q (128 q-rows, 8192 elems) into KsF, grab fragments ----
  ASYNC16(&KsF[tid * 8], qp + tid * 8);
  ASYNC16(&KsF[2048 + tid * 8], qp + 2048 + tid * 8);
  ASYNC16(&KsF[4096 + tid * 8], qp + 4096 + tid * 8);
  ASYNC16(&KsF[6144 + tid * 8], qp + 6144 + tid * 8);
  __syncthreads();
  bf16x8 qf[4];
  #pragma unroll
  for (int ks = 0; ks < 4; ks++)
    qf[ks] = *(const bf16x8*)&KsF[wid * 2048 + ks * 512 + hi * 256 + q5 * 8];
  __syncthreads();   // all waves done reading Q

  // ---- stage K0 / V0 ----
  ASYNC16(&KsF[tid * 8], kp + tid * 8);
  ASYNC16(&KsF[2048 + tid * 8], kp + 2048 + tid * 8);
  ASYNC16(&VsF[tid * 8], vp + tid * 8);
  ASYNC16(&VsF[2048 + tid * 8], vp + 2048 + tid * 8);
  __syncthreads();

  float m_run = -1e30f, l_run = 0.f;
  f32x16 oaccA = {}, oaccB = {};

  for (int kt = 0; kt < SEQ / 64; ++kt) {
    const int curo = (kt & 1) * 4096;
    if (kt + 1 < SEQ / 64) {
      const int nxo = curo ^ 4096;
      const bf16* gk = kp + (size_t)(kt + 1) * 4096;
      ASYNC16(&KsF[nxo + tid * 8], gk + tid * 8);
      ASYNC16(&KsF[nxo + 2048 + tid * 8], gk + 2048 + tid * 8);
      const bf16* gv = vp + (size_t)(kt + 1) * 4096;
      ASYNC16(&VsF[nxo + tid * 8], gv + tid * 8);
      ASYNC16(&VsF[nxo + 2048 + tid * 8], gv + 2048 + tid * 8);
    }

    // ---- swapped QK^T: 2 x (32kv x 32q), K = 4 ksteps of 16 ----
    f32x16 sc0 = {}, sc1 = {};
    __builtin_amdgcn_s_setprio(1);
    #pragma unroll
    for (int ks = 0; ks < 4; ks++) {
      const bf16x8 kf0 = *(const bf16x8*)&KsF[curo + ks * 512 + hi * 256 + q5 * 8];
      sc0 = __builtin_amdgcn_mfma_f32_32x32x16_bf16(kf0, qf[ks], sc0, 0, 0, 0);
      const bf16x8 kf1 = *(const bf16x8*)&KsF[curo + 2048 + ks * 512 + hi * 256 + q5 * 8];
      sc1 = __builtin_amdgcn_mfma_f32_32x32x16_bf16(kf1, qf[ks], sc1, 0, 0, 0);
    }
    __builtin_amdgcn_s_setprio(0);

    // ---- online softmax: 31 in-lane fmax + 1 shfl; defer-max (THR=8, log2) ----
    float pmax = sc0[0];
    #pragma unroll
    for (int r = 1; r < 16; r++) pmax = fmaxf(pmax, sc0[r]);
    #pragma unroll
    for (int r = 0; r < 16; r++) pmax = fmaxf(pmax, sc1[r]);
    pmax = fmaxf(pmax, __shfl_xor(pmax, 32));

    if (__any(pmax > m_run + 8.f)) {
      const float mnew = fmaxf(m_run, pmax);
      const float fac = exp2f(m_run - mnew);
      l_run *= fac;
      #pragma unroll
      for (int r = 0; r < 16; r++) { oaccA[r] *= fac; oaccB[r] *= fac; }
      m_run = mnew;
    }

    // ---- P = exp2(sc - m), packed into bf16x2 u32 register pairs ----
    // Pa[t][rg] = {kv = 8rg+4hi+0, +1}, Pb[t][rg] = {+2, +3} (within 32-kv tile t)
    int Pa[2][4], Pb[2][4];
    float psum = 0.f;
    #pragma unroll
    for (int t = 0; t < 2; t++) {
      #pragma unroll
      for (int rg = 0; rg < 4; rg++) {
        const float p0 = exp2f((t ? sc1 : sc0)[rg * 4 + 0] - m_run);
        const float p1 = exp2f((t ? sc1 : sc0)[rg * 4 + 1] - m_run);
        const float p2 = exp2f((t ? sc1 : sc0)[rg * 4 + 2] - m_run);
        const float p3 = exp2f((t ? sc1 : sc0)[rg * 4 + 3] - m_run);
        psum += (p0 + p1) + (p2 + p3);
        union { bf16x2 v; int u; } a, bb;
        a.v  = bf16x2{(bf16)p0, (bf16)p1};
        bb.v = bf16x2{(bf16)p2, (bf16)p3};
        Pa[t][rg] = a.u;
        Pb[t][rg] = bb.u;
      }
    }
    psum += __shfl_xor(psum, 32);
    l_run += psum;

    // ---- PV: assemble B-frag per kvs via lane^32 exchange, then mfma ----
    __builtin_amdgcn_s_setprio(1);
    #pragma unroll
    for (int t = 0; t < 2; t++) {
      #pragma unroll
      for (int k1 = 0; k1 < 2; k1++) {
        const int srcA  = hi ? Pa[t][2 * k1]     : Pa[t][2 * k1 + 1];
        const int srcB  = hi ? Pb[t][2 * k1]     : Pb[t][2 * k1 + 1];
        const int selfA = hi ? Pa[t][2 * k1 + 1] : Pa[t][2 * k1];
        const int selfB = hi ? Pb[t][2 * k1 + 1] : Pb[t][2 * k1];
        const int pulA = __shfl_xor(srcA, 32);
        const int pulB = __shfl_xor(srcB, 32);
        union { int4 i; bf16x8 v; } pf;
        pf.i.x = hi ? pulA : selfA;
        pf.i.y = hi ? pulB : selfB;
        pf.i.z = hi ? selfA : pulA;
        pf.i.w = hi ? selfB : pulB;
        const int kvs = t * 2 + k1;
        const bf16x8 vf0 = *(const bf16x8*)&VsF[curo + kvs * 512 + hi * 256 + q5 * 8];
        oaccA = __builtin_amdgcn_mfma_f32_32x32x16_bf16(vf0, pf.v, oaccA, 0, 0, 0);
        const bf16x8 vf1 = *(const bf16x8*)&VsF[curo + 2048 + kvs * 512 + hi * 256 + q5 * 8];
        oaccB = __builtin_amdgcn_mfma_f32_32x32x16_bf16(vf1, pf.v, oaccB, 0, 0, 0);
      }
    }
    __builtin_amdgcn_s_setprio(0);
    __syncthreads();   // compute on cur done + next tile's staging landed
  }

  // ---- epilogue: normalize, write attn output [B][S][D] (bf16, 8B vectors) ----
  const float inv = 1.0f / l_run;
  const int qrow = qt * 128 + wid * 32 + q5;
  bf16* ob = (bf16*)&O[((size_t)b * SEQ + qrow) * DM + h * HDIM + hi * 4];
  #pragma unroll
  for (int rg = 0; rg < 4; rg++) {
    bf16x4 ovA, ovB;
    #pragma unroll
    for (int e = 0; e < 4; e++) {
      ovA[e] = (bf16)(oaccA[rg * 4 + e] * inv);
      ovB[e] = (bf16)(oaccB[rg * 4 + e] * inv);
    }
    *(bf16x4*)(ob + rg * 8) = ovA;
    *(bf16x4*)(ob + 32 + rg * 8) = ovB;
  }
}

// ---------------- launcher ----------------
extern "C" void kernel_launch(void* const* d_in, const int* in_sizes, int n_in,
                              void* d_out, int out_size, void* d_ws, size_t ws_size,
                              hipStream_t stream) {
  (void)in_sizes; (void)n_in; (void)out_size; (void)ws_size;
  const float* x   = (const float*)d_in[0];
  const float* q_w = (const float*)d_in[1];
  const float* q_b = (const float*)d_in[2];
  const float* k_w = (const float*)d_in[3];
  const float* k_b = (const float*)d_in[4];
  const float* v_w = (const float*)d_in[5];
  const float* v_b = (const float*)d_in[6];
  const float* o_w = (const float*)d_in[7];
  const float* o_b = (const float*)d_in[8];
  float* out = (float*)d_out;

  char* p = (char*)d_ws;
  bf16* xb = (bf16*)p;  p += (size_t)MTOT * DM * 2;   // x bf16; reused later as attn output
  bf16* wt = (bf16*)p;  p += (size_t)4 * DM * DM * 2; // transposed bf16 weights [4][N][K]
  bf16* qq = (bf16*)p;  p += (size_t)MTOT * DM * 2;   // Q fragment-ordered (pre-scaled)
  bf16* kk = (bf16*)p;  p += (size_t)MTOT * DM * 2;   // K fragment-ordered
  bf16* vt = (bf16*)p;  p += (size_t)MTOT * DM * 2;   // V fragment-ordered

  cvt_x_kernel<<<1024, 256, 0, stream>>>(x, xb, MTOT * DM / 4);
  cvt_w_kernel<<<dim3(32, 32, 4), dim3(32, 8), 0, stream>>>(q_w, k_w, v_w, o_w, wt);

  // QKV projection: M=8192, N=3072 (q|k|v), K=1024 ; 24x64 tiles, XCD-swizzled 1D grid
  gemm128<0, 24><<<1536, 256, 0, stream>>>(xb, wt, q_b, k_b, v_b, qq, kk, vt, nullptr);

  // flash attention, writes [B][S][D] bf16 into xb (x no longer needed)
  attn_kernel<<<1024, 256, 0, stream>>>(qq, kk, vt, xb);

  // output projection: M=8192, N=1024, K=1024 ; 8x64 tiles, XCD-swizzled 1D grid
  gemm128<1, 8><<<512, 256, 0, stream>>>(xb, wt + (size_t)3 * DM * DM, o_b, nullptr, nullptr,
                                         nullptr, nullptr, nullptr, out);
}